// Round 1
// baseline (2019.350 us; speedup 1.0000x reference)
//
#include <hip/hip_runtime.h>
#include <math.h>

#define T_TOK 8192
#define CD 1024
#define HD 4096
#define NE 8
#define MAX_SLOTS 17408   // 16384 slots + 8*127 padding, rounded up
#define MAXM 8192         // max tokens (padded) per expert

#define BM 128
#define BN 128
#define BK 64
#define LDP 72            // LDS row pitch in bf16 elems (64 + 8 pad -> 2-way bank conflicts only)

typedef __bf16 bf16x8 __attribute__((ext_vector_type(8)));
typedef float f32x4 __attribute__((ext_vector_type(4)));

__device__ __forceinline__ unsigned short f2bf(float f) {
  union { float f; unsigned int u; } v; v.f = f;
  unsigned int u = v.u;
  return (unsigned short)((u + 0x7FFFu + ((u >> 16) & 1u)) >> 16);  // RNE
}

__device__ __forceinline__ float gelu_tanh(float x) {
  // jax.nn.gelu default: approximate=True (tanh form)
  float x3 = x * x * x;
  return 0.5f * x * (1.0f + tanhf(0.7978845608028654f * (x + 0.044715f * x3)));
}

// ---------------- router: fp32 logits -> softmax -> top2 -> weights ----------------
__global__ void router_kernel(const float* __restrict__ x, const float* __restrict__ gw,
                              int* __restrict__ meta, int* __restrict__ route_e,
                              float* __restrict__ route_w) {
  __shared__ float sgw[NE][CD];  // 32 KB
  for (int i = threadIdx.x; i < NE * CD; i += 256) sgw[i >> 10][i & (CD - 1)] = gw[i];
  __syncthreads();
  int wave = threadIdx.x >> 6, lane = threadIdx.x & 63;
  int t = blockIdx.x * 4 + wave;  // grid = T/4, exact
  const float* xr = x + (size_t)t * CD;
  float acc[NE];
#pragma unroll
  for (int e = 0; e < NE; e++) acc[e] = 0.f;
  for (int i = lane; i < CD; i += 64) {
    float xv = xr[i];
#pragma unroll
    for (int e = 0; e < NE; e++) acc[e] += xv * sgw[e][i];
  }
#pragma unroll
  for (int e = 0; e < NE; e++) {
    float v = acc[e];
#pragma unroll
    for (int off = 32; off > 0; off >>= 1) v += __shfl_xor(v, off);
    acc[e] = v;
  }
  if (lane == 0) {
    float mx = acc[0];
#pragma unroll
    for (int e = 1; e < NE; e++) mx = fmaxf(mx, acc[e]);
    float p[NE], s = 0.f;
#pragma unroll
    for (int e = 0; e < NE; e++) { p[e] = expf(acc[e] - mx); s += p[e]; }
    float inv = 1.0f / s;
#pragma unroll
    for (int e = 0; e < NE; e++) p[e] *= inv;
    int i0 = 0;
#pragma unroll
    for (int e = 1; e < NE; e++) if (p[e] > p[i0]) i0 = e;  // strict > : lowest index on ties (matches lax.top_k)
    int i1 = (i0 == 0) ? 1 : 0;
#pragma unroll
    for (int e = 0; e < NE; e++) if (e != i0 && p[e] > p[i1]) i1 = e;
    float den = p[i0] + p[i1] + 1e-8f;
    route_e[t * 2 + 0] = i0; route_e[t * 2 + 1] = i1;
    route_w[t * 2 + 0] = p[i0] / den; route_w[t * 2 + 1] = p[i1] / den;
    atomicAdd(&meta[i0], 1);
    atomicAdd(&meta[i1], 1);
  }
}

// meta layout (ints): [0:8) cnt, [8:16) offs, [16:24) mpad, [24:32) cursor
__global__ void offsets_kernel(int* meta) {
  if (threadIdx.x == 0 && blockIdx.x == 0) {
    int off = 0;
    for (int e = 0; e < NE; e++) {
      int pc = (meta[e] + 127) & ~127;  // pad each bucket to 128 rows
      meta[8 + e] = off;
      meta[16 + e] = pc;
      off += pc;
    }
  }
}

__global__ void scatter_kernel(const int* __restrict__ route_e, const float* __restrict__ route_w,
                               int* __restrict__ meta, int* __restrict__ slot_token,
                               float* __restrict__ slot_w) {
  int t = blockIdx.x * 256 + threadIdx.x;  // grid = T/256, exact
#pragma unroll
  for (int k = 0; k < 2; k++) {
    int e = route_e[t * 2 + k];
    float w = route_w[t * 2 + k];
    int idx = atomicAdd(&meta[24 + e], 1);
    int slot = meta[8 + e] + idx;
    slot_token[slot] = t;
    slot_w[slot] = w;
  }
}

// gather token rows -> bf16, zero-fill padded slots (token == -1)
__global__ void gather_kernel(const float* __restrict__ x, const int* __restrict__ slot_token,
                              unsigned short* __restrict__ xg) {
  int slot = blockIdx.x;
  int tkn = slot_token[slot];
  int i = threadIdx.x * 4;
  ushort4 o;
  if (tkn < 0) {
    o.x = 0; o.y = 0; o.z = 0; o.w = 0;
  } else {
    const float4 v = *(const float4*)(x + (size_t)tkn * CD + i);
    o.x = f2bf(v.x); o.y = f2bf(v.y); o.z = f2bf(v.z); o.w = f2bf(v.w);
  }
  *(ushort4*)(xg + (size_t)slot * CD + i) = o;
}

__global__ void cvt_kernel(const float* __restrict__ src, unsigned short* __restrict__ dst, int n4) {
  int i = blockIdx.x * 256 + threadIdx.x;
  if (i >= n4) return;
  const float4 v = *(const float4*)(src + (size_t)i * 4);
  ushort4 o;
  o.x = f2bf(v.x); o.y = f2bf(v.y); o.z = f2bf(v.z); o.w = f2bf(v.w);
  *(ushort4*)(dst + (size_t)i * 4) = o;
}

// ---------------- GEMM1: h = gelu(x_g @ w1^T + b1), K = 1024 ----------------
__global__ __launch_bounds__(256, 2)
void gemm1_kernel(const unsigned short* __restrict__ Ag,  // x_g [MAX_SLOTS][CD]
                  const unsigned short* __restrict__ Bg,  // w1b [HD][CD]
                  const float* __restrict__ bias,         // b1 + e*HD
                  unsigned short* __restrict__ Hout,      // h [MAXM][HD]
                  const int* __restrict__ meta, int e) {
  const int mpad = meta[16 + e];
  const int m0 = blockIdx.x * BM;
  if (m0 >= mpad) return;
  const int n0 = blockIdx.y * BN;
  const int off = meta[8 + e];
  const unsigned short* A = Ag + (size_t)(off + m0) * CD;
  const unsigned short* B = Bg + (size_t)n0 * CD;
  __shared__ unsigned short As[BM][LDP];
  __shared__ unsigned short Bs[BN][LDP];
  const int tid = threadIdx.x;
  const int lane = tid & 63, wave = tid >> 6;
  const int wm = wave >> 1, wn = wave & 1;
  const int r = lane & 15, q = lane >> 4;
  f32x4 acc[4][4];
#pragma unroll
  for (int i = 0; i < 4; i++)
#pragma unroll
    for (int j = 0; j < 4; j++) acc[i][j] = 0.f;

  for (int kt = 0; kt < CD / BK; kt++) {
#pragma unroll
    for (int c = 0; c < 4; c++) {
      int u = tid + c * 256;
      int row = u >> 3, kp = u & 7;
      *(int4*)&As[row][kp * 8] = *(const int4*)(A + (size_t)row * CD + kt * BK + kp * 8);
      *(int4*)&Bs[row][kp * 8] = *(const int4*)(B + (size_t)row * CD + kt * BK + kp * 8);
    }
    __syncthreads();
#pragma unroll
    for (int s = 0; s < 2; s++) {
      bf16x8 af[4], bfr[4];
#pragma unroll
      for (int i = 0; i < 4; i++) af[i] = *(const bf16x8*)&As[wm * 64 + i * 16 + r][s * 32 + q * 8];
#pragma unroll
      for (int j = 0; j < 4; j++) bfr[j] = *(const bf16x8*)&Bs[wn * 64 + j * 16 + r][s * 32 + q * 8];
#pragma unroll
      for (int i = 0; i < 4; i++)
#pragma unroll
        for (int j = 0; j < 4; j++)
          acc[i][j] = __builtin_amdgcn_mfma_f32_16x16x32_bf16(af[i], bfr[j], acc[i][j], 0, 0, 0);
    }
    __syncthreads();
  }
  // epilogue: C/D layout col = lane&15, row = quad*4 + reg
#pragma unroll
  for (int j = 0; j < 4; j++) {
    int n = n0 + wn * 64 + j * 16 + r;
    float bj = bias[n];
#pragma unroll
    for (int i = 0; i < 4; i++) {
#pragma unroll
      for (int g = 0; g < 4; g++) {
        int m = m0 + wm * 64 + i * 16 + q * 4 + g;  // always < mpad (padded), no bounds check
        float v = acc[i][j][g] + bj;
        Hout[(size_t)m * HD + n] = f2bf(gelu_tanh(v));
      }
    }
  }
}

// ---------------- GEMM2: out[token] += w_slot * (h @ w2^T + b2), K = 4096 ----------------
__global__ __launch_bounds__(256, 2)
void gemm2_kernel(const unsigned short* __restrict__ Hin,  // h [MAXM][HD]
                  const unsigned short* __restrict__ Bg,   // w2b [CD][HD]
                  const float* __restrict__ bias,          // b2 + e*CD
                  const int* __restrict__ meta, int e,
                  const int* __restrict__ slot_token, const float* __restrict__ slot_w,
                  float* __restrict__ out) {
  const int mpad = meta[16 + e];
  const int m0 = blockIdx.x * BM;
  if (m0 >= mpad) return;
  const int n0 = blockIdx.y * BN;
  const int off = meta[8 + e];
  const unsigned short* A = Hin + (size_t)m0 * HD;
  const unsigned short* B = Bg + (size_t)n0 * HD;
  __shared__ unsigned short As[BM][LDP];
  __shared__ unsigned short Bs[BN][LDP];
  const int tid = threadIdx.x;
  const int lane = tid & 63, wave = tid >> 6;
  const int wm = wave >> 1, wn = wave & 1;
  const int r = lane & 15, q = lane >> 4;
  f32x4 acc[4][4];
#pragma unroll
  for (int i = 0; i < 4; i++)
#pragma unroll
    for (int j = 0; j < 4; j++) acc[i][j] = 0.f;

  for (int kt = 0; kt < HD / BK; kt++) {
#pragma unroll
    for (int c = 0; c < 4; c++) {
      int u = tid + c * 256;
      int row = u >> 3, kp = u & 7;
      *(int4*)&As[row][kp * 8] = *(const int4*)(A + (size_t)row * HD + kt * BK + kp * 8);
      *(int4*)&Bs[row][kp * 8] = *(const int4*)(B + (size_t)row * HD + kt * BK + kp * 8);
    }
    __syncthreads();
#pragma unroll
    for (int s = 0; s < 2; s++) {
      bf16x8 af[4], bfr[4];
#pragma unroll
      for (int i = 0; i < 4; i++) af[i] = *(const bf16x8*)&As[wm * 64 + i * 16 + r][s * 32 + q * 8];
#pragma unroll
      for (int j = 0; j < 4; j++) bfr[j] = *(const bf16x8*)&Bs[wn * 64 + j * 16 + r][s * 32 + q * 8];
#pragma unroll
      for (int i = 0; i < 4; i++)
#pragma unroll
        for (int j = 0; j < 4; j++)
          acc[i][j] = __builtin_amdgcn_mfma_f32_16x16x32_bf16(af[i], bfr[j], acc[i][j], 0, 0, 0);
    }
    __syncthreads();
  }
#pragma unroll
  for (int i = 0; i < 4; i++) {
#pragma unroll
    for (int g = 0; g < 4; g++) {
      int m = m0 + wm * 64 + i * 16 + q * 4 + g;
      int slot = off + m;
      int tkn = slot_token[slot];
      if (tkn < 0) continue;  // padded slot
      float wgt = slot_w[slot];
      float* orow = out + (size_t)tkn * CD;
#pragma unroll
      for (int j = 0; j < 4; j++) {
        int n = n0 + wn * 64 + j * 16 + r;
        atomicAdd(&orow[n], wgt * (acc[i][j][g] + bias[n]));
      }
    }
  }
}

extern "C" void kernel_launch(void* const* d_in, const int* in_sizes, int n_in,
                              void* d_out, int out_size, void* d_ws, size_t ws_size,
                              hipStream_t stream) {
  const float* x  = (const float*)d_in[0];
  const float* gw = (const float*)d_in[1];
  const float* w1 = (const float*)d_in[2];
  const float* b1 = (const float*)d_in[3];
  const float* w2 = (const float*)d_in[4];
  const float* b2 = (const float*)d_in[5];
  float* out = (float*)d_out;

  char* p = (char*)d_ws;
  size_t o = 0;
  int* meta = (int*)p;                   o = 256;
  int* slot_token = (int*)(p + o);       o += (size_t)MAX_SLOTS * 4;
  float* slot_w = (float*)(p + o);       o += (size_t)MAX_SLOTS * 4;
  int* route_e = (int*)(p + o);          o += (size_t)T_TOK * 8;
  float* route_w = (float*)(p + o);      o += (size_t)T_TOK * 8;
  o = (o + 255) & ~(size_t)255;
  unsigned short* xg = (unsigned short*)(p + o);  o += (size_t)MAX_SLOTS * CD * 2;
  unsigned short* h  = (unsigned short*)(p + o);  o += (size_t)MAXM * HD * 2;
  unsigned short* w1b = (unsigned short*)(p + o); o += (size_t)HD * CD * 2;
  unsigned short* w2b = (unsigned short*)(p + o); o += (size_t)CD * HD * 2;
  if (ws_size < o) return;  // workspace too small: fail validation cleanly, no OOB writes

  hipMemsetAsync(meta, 0, 256, stream);
  hipMemsetAsync(slot_token, 0xFF, (size_t)MAX_SLOTS * 4, stream);  // -1
  hipMemsetAsync(out, 0, (size_t)out_size * 4, stream);

  router_kernel<<<T_TOK / 4, 256, 0, stream>>>(x, gw, meta, route_e, route_w);
  offsets_kernel<<<1, 64, 0, stream>>>(meta);
  scatter_kernel<<<T_TOK / 256, 256, 0, stream>>>(route_e, route_w, meta, slot_token, slot_w);
  gather_kernel<<<MAX_SLOTS, 256, 0, stream>>>(x, slot_token, xg);

  for (int e = 0; e < NE; e++) {
    cvt_kernel<<<(HD * CD / 4) / 256, 256, 0, stream>>>(w1 + (size_t)e * HD * CD, w1b, HD * CD / 4);
    cvt_kernel<<<(CD * HD / 4) / 256, 256, 0, stream>>>(w2 + (size_t)e * CD * HD, w2b, CD * HD / 4);
    gemm1_kernel<<<dim3(MAXM / BM, HD / BN), 256, 0, stream>>>(xg, w1b, b1 + (size_t)e * HD, h, meta, e);
    gemm2_kernel<<<dim3(MAXM / BM, CD / BN), 256, 0, stream>>>(h, w2b, b2 + (size_t)e * CD, meta, e,
                                                               slot_token, slot_w, out);
  }
}

// Round 2
// 1209.105 us; speedup vs baseline: 1.6701x; 1.6701x over previous
//
#include <hip/hip_runtime.h>
#include <math.h>

#define T_TOK 8192
#define CD 1024
#define HD 4096
#define NE 8
#define MAX_SLOTS 17408   // 16384 slots + 8*127 padding, rounded up
#define MAXM_FB 8192      // fallback path: max padded rows per expert

#define BM 128
#define BN 128
#define BK 64             // bf16 elems per K-tile (128 B rows in LDS)

typedef __bf16 bf16x8 __attribute__((ext_vector_type(8)));
typedef float f32x4 __attribute__((ext_vector_type(4)));

__device__ __forceinline__ unsigned short f2bf(float f) {
  union { float f; unsigned int u; } v; v.f = f;
  unsigned int u = v.u;
  return (unsigned short)((u + 0x7FFFu + ((u >> 16) & 1u)) >> 16);  // RNE
}

__device__ __forceinline__ float gelu_fast(float x) {
  // tanh-form gelu rewritten as x * sigmoid(2z): exact same math, ~8 VALU ops
  float x3 = x * x * x;
  float z = 0.7978845608028654f * (x + 0.044715f * x3);
  float ez = __expf(-2.0f * z);
  return x * __builtin_amdgcn_rcpf(1.0f + ez);
}

// async global->LDS, 16 B per lane; LDS dest = wave-uniform base + lane*16
__device__ __forceinline__ void glds16(const void* g, void* l) {
  __builtin_amdgcn_global_load_lds((__attribute__((address_space(1))) void*)g,
                                   (__attribute__((address_space(3))) void*)l,
                                   16, 0, 0);
}

// ---------------- router: fp32 logits -> softmax -> top2 -> weights ----------------
// block = 256 (4 waves), 16 tokens per block (4 per wave), grid = T/16
__global__ void router_kernel(const float* __restrict__ x, const float* __restrict__ gw,
                              int* __restrict__ meta, int* __restrict__ route_e,
                              float* __restrict__ route_w) {
  __shared__ float4 sgw4[NE * (CD / 4)];  // 32 KB
  const int tid = threadIdx.x;
  for (int idx = tid; idx < NE * CD / 4; idx += 256) sgw4[idx] = ((const float4*)gw)[idx];
  __syncthreads();
  const int wave = tid >> 6, lane = tid & 63;
  const int t0 = blockIdx.x * 16 + wave * 4;
#pragma unroll
  for (int tt = 0; tt < 4; tt++) {
    const int t = t0 + tt;
    const float4* xr4 = (const float4*)(x + (size_t)t * CD);
    float4 xv[4];
#pragma unroll
    for (int it = 0; it < 4; it++) xv[it] = xr4[it * 64 + lane];
    float acc[NE];
#pragma unroll
    for (int e = 0; e < NE; e++) acc[e] = 0.f;
#pragma unroll
    for (int it = 0; it < 4; it++) {
#pragma unroll
      for (int e = 0; e < NE; e++) {
        float4 g = sgw4[e * 256 + it * 64 + lane];
        acc[e] += xv[it].x * g.x + xv[it].y * g.y + xv[it].z * g.z + xv[it].w * g.w;
      }
    }
#pragma unroll
    for (int e = 0; e < NE; e++) {
      float v = acc[e];
#pragma unroll
      for (int off = 32; off > 0; off >>= 1) v += __shfl_xor(v, off);
      acc[e] = v;
    }
    if (lane == 0) {
      float mx = acc[0];
#pragma unroll
      for (int e = 1; e < NE; e++) mx = fmaxf(mx, acc[e]);
      float p[NE], s = 0.f;
#pragma unroll
      for (int e = 0; e < NE; e++) { p[e] = __expf(acc[e] - mx); s += p[e]; }
      float inv = 1.0f / s;
#pragma unroll
      for (int e = 0; e < NE; e++) p[e] *= inv;
      int i0 = 0;
#pragma unroll
      for (int e = 1; e < NE; e++) if (p[e] > p[i0]) i0 = e;  // strict >: lowest idx on tie
      int i1 = (i0 == 0) ? 1 : 0;
#pragma unroll
      for (int e = 0; e < NE; e++) if (e != i0 && p[e] > p[i1]) i1 = e;
      float den = p[i0] + p[i1] + 1e-8f;
      route_e[t * 2 + 0] = i0; route_e[t * 2 + 1] = i1;
      route_w[t * 2 + 0] = p[i0] / den; route_w[t * 2 + 1] = p[i1] / den;
      atomicAdd(&meta[i0], 1);
      atomicAdd(&meta[i1], 1);
    }
  }
}

// meta layout (ints): [0:8) cnt, [8:16) offs, [16:24) mpad, [24:32) cursor
__global__ void offsets_kernel(int* meta) {
  if (threadIdx.x == 0 && blockIdx.x == 0) {
    int off = 0;
    for (int e = 0; e < NE; e++) {
      int pc = (meta[e] + 127) & ~127;
      meta[8 + e] = off;
      meta[16 + e] = pc;
      off += pc;
    }
  }
}

__global__ void scatter_kernel(const int* __restrict__ route_e, const float* __restrict__ route_w,
                               int* __restrict__ meta, int* __restrict__ slot_token,
                               float* __restrict__ slot_w) {
  int t = blockIdx.x * 256 + threadIdx.x;
#pragma unroll
  for (int k = 0; k < 2; k++) {
    int e = route_e[t * 2 + k];
    float w = route_w[t * 2 + k];
    int idx = atomicAdd(&meta[24 + e], 1);
    int slot = meta[8 + e] + idx;
    slot_token[slot] = t;
    slot_w[slot] = w;
  }
}

__global__ void gather_kernel(const float* __restrict__ x, const int* __restrict__ slot_token,
                              unsigned short* __restrict__ xg) {
  int slot = blockIdx.x;
  int tkn = slot_token[slot];
  int i = threadIdx.x * 4;
  ushort4 o;
  if (tkn < 0) {
    o.x = 0; o.y = 0; o.z = 0; o.w = 0;
  } else {
    const float4 v = *(const float4*)(x + (size_t)tkn * CD + i);
    o.x = f2bf(v.x); o.y = f2bf(v.y); o.z = f2bf(v.z); o.w = f2bf(v.w);
  }
  *(ushort4*)(xg + (size_t)slot * CD + i) = o;
}

__global__ void cvt_kernel(const float* __restrict__ src, unsigned short* __restrict__ dst, int n4) {
  int i = blockIdx.x * 256 + threadIdx.x;
  if (i >= n4) return;
  const float4 v = *(const float4*)(src + (size_t)i * 4);
  ushort4 o;
  o.x = f2bf(v.x); o.y = f2bf(v.y); o.z = f2bf(v.z); o.w = f2bf(v.w);
  *(ushort4*)(dst + (size_t)i * 4) = o;
}

// ======================= GEMM1: h = gelu(x_g @ w1^T + b1), K = CD =======================
// XOR-swizzled LDS: granule gg of row holds global granule gg ^ (row & 7). 16B granules,
// rows of 64 bf16 (128 B). Satisfies global_load_lds contiguity; fragment reads stay
// perfectly bank-balanced (each bank hit exactly 8x per wave64 ds_read_b128).
__global__ __launch_bounds__(256, 2)
void gemm1_kernel(const unsigned short* __restrict__ Ag,   // x_g [MAX_SLOTS][CD]
                  const unsigned short* __restrict__ Ball, // bf16 w1, [e][HD][CD] or single expert
                  size_t b_estride,                        // HD*CD fused, 0 fallback
                  const float* __restrict__ b1,            // full b1 [NE][HD]
                  unsigned short* __restrict__ Hout,       // h
                  int h_slot,                              // 1: h indexed by slot, 0: by m
                  const int* __restrict__ meta, int e0) {
  const int e = e0 + blockIdx.z;
  const int mpad = meta[16 + e];
  const int m0 = blockIdx.x * BM;
  if (m0 >= mpad) return;
  const int n0 = blockIdx.y * BN;
  const int off = meta[8 + e];
  const unsigned short* A = Ag + (size_t)(off + m0) * CD;
  const unsigned short* B = Ball + (size_t)e * b_estride + (size_t)n0 * CD;
  const float* bias = b1 + (size_t)e * HD;
  const size_t hbase = (size_t)(h_slot ? (off + m0) : m0);

  __shared__ unsigned short As[BM * BK];
  __shared__ unsigned short Bs[BN * BK];
  const int tid = threadIdx.x;
  const int lane = tid & 63, wave = tid >> 6;
  const int wm = wave >> 1, wn = wave & 1;
  const int r = lane & 15, qq = lane >> 4;
  const int lr = lane >> 3;              // 0..7 row within 8-row staging chunk
  const int gc = (lane & 7) ^ lr;        // swizzled global granule for staging
  const int rx = r & 7;                  // row swizzle key for fragment reads

  f32x4 acc[4][4];
#pragma unroll
  for (int i = 0; i < 4; i++)
#pragma unroll
    for (int j = 0; j < 4; j++) acc[i][j] = 0.f;

  for (int kt = 0; kt < CD / BK; kt++) {
#pragma unroll
    for (int c = 0; c < 4; c++) {
      const int rowb = wave * 32 + c * 8;
      glds16(A + (size_t)(rowb + lr) * CD + kt * BK + gc * 8, &As[rowb * BK]);
      glds16(B + (size_t)(rowb + lr) * CD + kt * BK + gc * 8, &Bs[rowb * BK]);
    }
    __syncthreads();
#pragma unroll
    for (int s = 0; s < 2; s++) {
      bf16x8 af[4], bfr[4];
#pragma unroll
      for (int i = 0; i < 4; i++)
        af[i] = *(const bf16x8*)&As[(wm * 64 + i * 16 + r) * BK + ((((s << 2) | qq) ^ rx) << 3)];
#pragma unroll
      for (int j = 0; j < 4; j++)
        bfr[j] = *(const bf16x8*)&Bs[(wn * 64 + j * 16 + r) * BK + ((((s << 2) | qq) ^ rx) << 3)];
#pragma unroll
      for (int i = 0; i < 4; i++)
#pragma unroll
        for (int j = 0; j < 4; j++)
          acc[i][j] = __builtin_amdgcn_mfma_f32_16x16x32_bf16(af[i], bfr[j], acc[i][j], 0, 0, 0);
    }
    __syncthreads();
  }
  // epilogue: C/D layout col = lane&15, row = quad*4 + reg
#pragma unroll
  for (int j = 0; j < 4; j++) {
    int n = n0 + wn * 64 + j * 16 + r;
    float bj = bias[n];
#pragma unroll
    for (int i = 0; i < 4; i++) {
#pragma unroll
      for (int g = 0; g < 4; g++) {
        int ml = wm * 64 + i * 16 + qq * 4 + g;
        Hout[(hbase + ml) * (size_t)HD + n] = f2bf(gelu_fast(acc[i][j][g] + bj));
      }
    }
  }
}

// =============== GEMM2: out[token] += w_slot * (h @ w2^T + b2), K = HD ===============
__global__ __launch_bounds__(256, 2)
void gemm2_kernel(const unsigned short* __restrict__ Hin, int h_slot,
                  const unsigned short* __restrict__ Ball, size_t b_estride,
                  const float* __restrict__ b2,
                  const int* __restrict__ meta, int e0,
                  const int* __restrict__ slot_token, const float* __restrict__ slot_w,
                  float* __restrict__ out) {
  const int e = e0 + blockIdx.z;
  const int mpad = meta[16 + e];
  const int m0 = blockIdx.x * BM;
  if (m0 >= mpad) return;
  const int n0 = blockIdx.y * BN;
  const int off = meta[8 + e];
  const unsigned short* A = Hin + (size_t)(h_slot ? (off + m0) : m0) * HD;
  const unsigned short* B = Ball + (size_t)e * b_estride + (size_t)n0 * HD;
  const float* bias = b2 + (size_t)e * CD;

  __shared__ unsigned short As[BM * BK];
  __shared__ unsigned short Bs[BN * BK];
  const int tid = threadIdx.x;
  const int lane = tid & 63, wave = tid >> 6;
  const int wm = wave >> 1, wn = wave & 1;
  const int r = lane & 15, qq = lane >> 4;
  const int lr = lane >> 3;
  const int gc = (lane & 7) ^ lr;
  const int rx = r & 7;

  f32x4 acc[4][4];
#pragma unroll
  for (int i = 0; i < 4; i++)
#pragma unroll
    for (int j = 0; j < 4; j++) acc[i][j] = 0.f;

  for (int kt = 0; kt < HD / BK; kt++) {
#pragma unroll
    for (int c = 0; c < 4; c++) {
      const int rowb = wave * 32 + c * 8;
      glds16(A + (size_t)(rowb + lr) * HD + kt * BK + gc * 8, &As[rowb * BK]);
      glds16(B + (size_t)(rowb + lr) * HD + kt * BK + gc * 8, &Bs[rowb * BK]);
    }
    __syncthreads();
#pragma unroll
    for (int s = 0; s < 2; s++) {
      bf16x8 af[4], bfr[4];
#pragma unroll
      for (int i = 0; i < 4; i++)
        af[i] = *(const bf16x8*)&As[(wm * 64 + i * 16 + r) * BK + ((((s << 2) | qq) ^ rx) << 3)];
#pragma unroll
      for (int j = 0; j < 4; j++)
        bfr[j] = *(const bf16x8*)&Bs[(wn * 64 + j * 16 + r) * BK + ((((s << 2) | qq) ^ rx) << 3)];
#pragma unroll
      for (int i = 0; i < 4; i++)
#pragma unroll
        for (int j = 0; j < 4; j++)
          acc[i][j] = __builtin_amdgcn_mfma_f32_16x16x32_bf16(af[i], bfr[j], acc[i][j], 0, 0, 0);
    }
    __syncthreads();
  }
#pragma unroll
  for (int i = 0; i < 4; i++) {
#pragma unroll
    for (int g = 0; g < 4; g++) {
      int ml = wm * 64 + i * 16 + qq * 4 + g;
      int slot = off + m0 + ml;
      int tkn = slot_token[slot];
      if (tkn < 0) continue;
      float wgt = slot_w[slot];
      float* orow = out + (size_t)tkn * CD;
#pragma unroll
      for (int j = 0; j < 4; j++) {
        int n = n0 + wn * 64 + j * 16 + r;
        atomicAdd(&orow[n], wgt * (acc[i][j][g] + bias[n]));
      }
    }
  }
}

extern "C" void kernel_launch(void* const* d_in, const int* in_sizes, int n_in,
                              void* d_out, int out_size, void* d_ws, size_t ws_size,
                              hipStream_t stream) {
  const float* x  = (const float*)d_in[0];
  const float* gw = (const float*)d_in[1];
  const float* w1 = (const float*)d_in[2];
  const float* b1 = (const float*)d_in[3];
  const float* w2 = (const float*)d_in[4];
  const float* b2 = (const float*)d_in[5];
  float* out = (float*)d_out;

  char* p = (char*)d_ws;
  size_t o = 0;
  int* meta = (int*)p;                   o = 256;
  int* slot_token = (int*)(p + o);       o += (size_t)MAX_SLOTS * 4;
  float* slot_w = (float*)(p + o);       o += (size_t)MAX_SLOTS * 4;
  int* route_e = (int*)(p + o);          o += (size_t)T_TOK * 8;
  float* route_w = (float*)(p + o);      o += (size_t)T_TOK * 8;
  o = (o + 255) & ~(size_t)255;
  unsigned short* xg = (unsigned short*)(p + o);  o += (size_t)MAX_SLOTS * CD * 2;
  const size_t o_common = o;

  // fused layout: all-expert weights + slot-indexed h
  size_t of = o_common;
  unsigned short* w1b_f = (unsigned short*)(p + of); of += (size_t)NE * HD * CD * 2;
  unsigned short* w2b_f = (unsigned short*)(p + of); of += (size_t)NE * CD * HD * 2;
  unsigned short* h_f   = (unsigned short*)(p + of); of += (size_t)MAX_SLOTS * HD * 2;
  // fallback layout: per-expert reuse
  size_t ob = o_common;
  unsigned short* w1b_s = (unsigned short*)(p + ob); ob += (size_t)HD * CD * 2;
  unsigned short* w2b_s = (unsigned short*)(p + ob); ob += (size_t)CD * HD * 2;
  unsigned short* h_s   = (unsigned short*)(p + ob); ob += (size_t)MAXM_FB * HD * 2;

  const bool fused = (ws_size >= of);
  if (!fused && ws_size < ob) return;  // workspace too small: fail cleanly

  hipMemsetAsync(meta, 0, 256, stream);
  hipMemsetAsync(slot_token, 0xFF, (size_t)MAX_SLOTS * 4, stream);  // -1
  hipMemsetAsync(out, 0, (size_t)out_size * 4, stream);

  router_kernel<<<T_TOK / 16, 256, 0, stream>>>(x, gw, meta, route_e, route_w);
  offsets_kernel<<<1, 64, 0, stream>>>(meta);
  scatter_kernel<<<T_TOK / 256, 256, 0, stream>>>(route_e, route_w, meta, slot_token, slot_w);
  gather_kernel<<<MAX_SLOTS, 256, 0, stream>>>(x, slot_token, xg);

  if (fused) {
    const int n4w = NE * HD * CD / 4;
    cvt_kernel<<<n4w / 256, 256, 0, stream>>>(w1, w1b_f, n4w);
    cvt_kernel<<<n4w / 256, 256, 0, stream>>>(w2, w2b_f, n4w);
    gemm1_kernel<<<dim3(MAXM_FB / BM, HD / BN, NE), 256, 0, stream>>>(
        xg, w1b_f, (size_t)HD * CD, b1, h_f, 1, meta, 0);
    gemm2_kernel<<<dim3(MAXM_FB / BM, CD / BN, NE), 256, 0, stream>>>(
        h_f, 1, w2b_f, (size_t)CD * HD, b2, meta, 0, slot_token, slot_w, out);
  } else {
    const int n4e = HD * CD / 4;
    for (int e = 0; e < NE; e++) {
      cvt_kernel<<<n4e / 256, 256, 0, stream>>>(w1 + (size_t)e * HD * CD, w1b_s, n4e);
      cvt_kernel<<<n4e / 256, 256, 0, stream>>>(w2 + (size_t)e * CD * HD, w2b_s, n4e);
      gemm1_kernel<<<dim3(MAXM_FB / BM, HD / BN, 1), 256, 0, stream>>>(
          xg, w1b_s, 0, b1, h_s, 0, meta, e);
      gemm2_kernel<<<dim3(MAXM_FB / BM, CD / BN, 1), 256, 0, stream>>>(
          h_s, 0, w2b_s, 0, b2, meta, e, slot_token, slot_w, out);
    }
  }
}